// Round 1
// baseline (573.435 us; speedup 1.0000x reference)
//
#include <hip/hip_runtime.h>

// ShootingBlockMNModel1: 20 GD steps on 12-dim Theta=(T1,b1,T2,b2), each step a
// reduction over K=1M samples; then analytic reverse-mode through the scan.
//
// ws layout:
//   double stats[21][40]   @ 0        (36 used/row; zeroed via hipMemsetAsync)
//     [0..3]  PH  = sum p_a h_b        (a*2+b)
//     [4..5]  SP  = sum p_a
//     [6..9]  WQ  = sum w_c q_d        (c*2+d)
//     [10..11] W  = sum w_c
//     [12..19] PSQ= sum p_a s_b q_d    (a*4+b*2+d)
//     [20..23] PS = sum p_a s_b        (a*2+b)
//     [24..29] RQQ= sum r_c q_d q_f    (c*3 + {00:0,01/10:1,11:2})
//     [30..33] RQ = sum r_c q_d        (c*2+d)
//     [34..35] R  = sum r_c
//   float theta[21][12]    @ 6720     ([T1(4),b1(2),T2(4),b2(2)], row-major)
//   float lam[21][12]      after theta (adjoints lambda_k)
//   float ksym[16], ksymb[4] after lam (symmetrized inv_Kbar / inv_Kbar_b)

#define LR 0.25f
#define NIT 20
#define STRIDE_STATS 40

__device__ __forceinline__ float fast_tanh(float x){
    float e = __expf(2.0f*x);          // x>>0: e=inf -> 1; x<<0: e=0 -> -1
    return 1.0f - 2.0f/(e+1.0f);
}

__global__ void k_setup(const float* __restrict__ t1i, const float* __restrict__ b1i,
                        const float* __restrict__ t2i, const float* __restrict__ b2i,
                        const float* __restrict__ invK, const float* __restrict__ invKb,
                        float* __restrict__ theta, float* __restrict__ ksym,
                        float* __restrict__ ksymb){
    if(threadIdx.x==0 && blockIdx.x==0){
        theta[0]=t1i[0]; theta[1]=t1i[1]; theta[2]=t1i[2]; theta[3]=t1i[3];
        theta[4]=b1i[0]; theta[5]=b1i[1];
        theta[6]=t2i[0]; theta[7]=t2i[1]; theta[8]=t2i[2]; theta[9]=t2i[3];
        theta[10]=b2i[0]; theta[11]=b2i[1];
        for(int a=0;a<4;a++)
            for(int b=0;b<4;b++)
                ksym[a*4+b] = 0.5f*(invK[a*4+b]+invK[b*4+a]);
        for(int a=0;a<2;a++)
            for(int b=0;b<2;b++)
                ksymb[a*2+b] = 0.5f*(invKb[a*2+b]+invKb[b*2+a]);
    }
}

// one pass over all samples at Theta_k: accumulate gradient stats + Hessian stats
__global__ __launch_bounds__(256) void k_reduce(const float2* __restrict__ q,
                                                const float2* __restrict__ p,
                                                int K,
                                                const float* __restrict__ theta,
                                                double* __restrict__ stats){
    const float t1_00=theta[0], t1_01=theta[1], t1_10=theta[2], t1_11=theta[3];
    const float t2_00=theta[6], t2_01=theta[7], t2_10=theta[8], t2_11=theta[9];
    const float b2_0=theta[10], b2_1=theta[11];

    float acc[36];
    #pragma unroll
    for(int j=0;j<36;j++) acc[j]=0.0f;

    const int tid = blockIdx.x*blockDim.x + threadIdx.x;
    const int nth = gridDim.x*blockDim.x;
    for(int i=tid;i<K;i+=nth){
        float2 qq = q[i]; float2 pp = p[i];
        float q0=qq.x, q1=qq.y, p0=pp.x, p1=pp.y;
        float u0 = t2_00*q0 + t2_01*q1 + b2_0;
        float u1 = t2_10*q0 + t2_11*q1 + b2_1;
        float h0 = fast_tanh(u0), h1 = fast_tanh(u1);
        float s0 = 1.0f-h0*h0, s1 = 1.0f-h1*h1;
        float a0 = t1_00*p0 + t1_10*p1;      // (T1^T p)
        float a1 = t1_01*p0 + t1_11*p1;
        float w0 = a0*s0, w1 = a1*s1;
        float r0 = -2.0f*a0*h0*s0, r1 = -2.0f*a1*h1*s1;

        acc[0]+=p0*h0; acc[1]+=p0*h1; acc[2]+=p1*h0; acc[3]+=p1*h1;
        acc[4]+=p0;    acc[5]+=p1;
        acc[6]+=w0*q0; acc[7]+=w0*q1; acc[8]+=w1*q0; acc[9]+=w1*q1;
        acc[10]+=w0;   acc[11]+=w1;
        float ps00=p0*s0, ps01=p0*s1, ps10=p1*s0, ps11=p1*s1;
        acc[12]+=ps00*q0; acc[13]+=ps00*q1; acc[14]+=ps01*q0; acc[15]+=ps01*q1;
        acc[16]+=ps10*q0; acc[17]+=ps10*q1; acc[18]+=ps11*q0; acc[19]+=ps11*q1;
        acc[20]+=ps00; acc[21]+=ps01; acc[22]+=ps10; acc[23]+=ps11;
        float r0q0=r0*q0, r1q0=r1*q0;
        acc[24]+=r0q0*q0; acc[25]+=r0q0*q1; acc[26]+=r0*q1*q1;
        acc[27]+=r1q0*q0; acc[28]+=r1q0*q1; acc[29]+=r1*q1*q1;
        acc[30]+=r0q0; acc[31]+=r0*q1; acc[32]+=r1q0; acc[33]+=r1*q1;
        acc[34]+=r0; acc[35]+=r1;
    }

    __shared__ float red[4][36];
    const int lane = threadIdx.x & 63;
    const int wave = threadIdx.x >> 6;
    #pragma unroll
    for(int j=0;j<36;j++){
        float v = acc[j];
        v += __shfl_down(v,32); v += __shfl_down(v,16); v += __shfl_down(v,8);
        v += __shfl_down(v,4);  v += __shfl_down(v,2);  v += __shfl_down(v,1);
        if(lane==0) red[wave][j]=v;
    }
    __syncthreads();
    if(threadIdx.x < 36){
        double s = (double)red[0][threadIdx.x] + (double)red[1][threadIdx.x]
                 + (double)red[2][threadIdx.x] + (double)red[3][threadIdx.x];
        atomicAdd(&stats[threadIdx.x], s);
    }
}

__device__ __forceinline__ void compute_grad(const double* __restrict__ s,
                                             const float* __restrict__ th,
                                             const float* __restrict__ ksym,
                                             const float* __restrict__ ksymb,
                                             float c, float* g){
    const float Ivec[4]={1.f,0.f,0.f,1.f};
    for(int j=0;j<4;j++){
        float kv=0.f;
        for(int m=0;m<4;m++) kv += ksym[j*4+m]*th[m];
        g[j] = kv - c*(float)s[j];
    }
    for(int i2=0;i2<2;i2++)
        g[4+i2] = ksymb[i2*2+0]*th[4] + ksymb[i2*2+1]*th[5] - c*(float)s[4+i2];
    for(int j=0;j<4;j++){
        float kv=0.f;
        for(int m=0;m<4;m++) kv += ksym[j*4+m]*(th[6+m]-Ivec[m]);
        g[6+j] = kv - c*(float)s[6+j];
    }
    for(int i2=0;i2<2;i2++)
        g[10+i2] = ksymb[i2*2+0]*th[10] + ksymb[i2*2+1]*th[11] - c*(float)s[10+i2];
}

__global__ void k_update(const double* __restrict__ stats, const float* __restrict__ theta,
                         float* __restrict__ theta_next, const float* __restrict__ ksym,
                         const float* __restrict__ ksymb, float c){
    if(threadIdx.x==0 && blockIdx.x==0){
        float g[12];
        compute_grad(stats, theta, ksym, ksymb, c, g);
        for(int j=0;j<12;j++) theta_next[j] = theta[j] - LR*g[j];
    }
}

__device__ __forceinline__ float rqq6(const double* __restrict__ s, int c2, int f, int d){
    return (float)s[24 + c2*3 + (f+d)];   // (0,0)->0, (0,1)/(1,0)->1, (1,1)->2
}

// lambda_20 = g(Theta_20); lambda_k = lambda_{k+1} - LR * H_k lambda_{k+1}
__global__ void k_backward(const double* __restrict__ statsAll,
                           const float* __restrict__ thetaAll,
                           float* __restrict__ lamAll,
                           const float* __restrict__ ksym,
                           const float* __restrict__ ksymb, float c){
    if(threadIdx.x!=0 || blockIdx.x!=0) return;
    float lv[12];
    compute_grad(statsAll + 20*STRIDE_STATS, thetaAll + 20*12, ksym, ksymb, c, lv);
    for(int j=0;j<12;j++) lamAll[20*12+j]=lv[j];
    for(int k=NIT-1;k>=0;k--){
        const double* s = statsAll + k*STRIDE_STATS;
        float H[12];
        // T1 block: Ksym*L1 - c*( sum_d PSQ[a][b][d]*L2[b][d] + PS[a][b]*lb2[b] )
        for(int a=0;a<2;a++)for(int b=0;b<2;b++){
            int j=a*2+b;
            float data = (float)s[12+a*4+b*2+0]*lv[6+b*2+0]
                       + (float)s[12+a*4+b*2+1]*lv[6+b*2+1]
                       + (float)s[20+a*2+b]*lv[10+b];
            float kv=0.f;
            for(int m=0;m<4;m++) kv += ksym[j*4+m]*lv[m];
            H[j]=kv - c*data;
        }
        // b1 block: kinetic only
        for(int i2=0;i2<2;i2++)
            H[4+i2] = ksymb[i2*2+0]*lv[4] + ksymb[i2*2+1]*lv[5];
        // T2 block
        for(int cc=0;cc<2;cc++)for(int d=0;d<2;d++){
            int j=cc*2+d;
            float term1 = lv[0+cc]*(float)s[12+0*4+cc*2+d] + lv[2+cc]*(float)s[12+1*4+cc*2+d];
            float term2 = lv[6+cc*2+0]*rqq6(s,cc,0,d) + lv[6+cc*2+1]*rqq6(s,cc,1,d);
            float term3 = lv[10+cc]*(float)s[30+cc*2+d];
            float kv=0.f;
            for(int m=0;m<4;m++) kv += ksym[j*4+m]*lv[6+m];
            H[6+j]=kv - c*(term1+term2+term3);
        }
        // b2 block
        for(int cc=0;cc<2;cc++){
            float z1 = lv[0+cc]*(float)s[20+0*2+cc] + lv[2+cc]*(float)s[20+1*2+cc];
            float z2 = lv[6+cc*2+0]*(float)s[30+cc*2+0] + lv[6+cc*2+1]*(float)s[30+cc*2+1];
            float z3 = lv[10+cc]*(float)s[34+cc];
            float kv = ksymb[cc*2+0]*lv[10] + ksymb[cc*2+1]*lv[11];
            H[10+cc]=kv - c*(z1+z2+z3);
        }
        for(int j=0;j<12;j++) lv[j] -= LR*H[j];
        for(int j=0;j<12;j++) lamAll[k*12+j]=lv[j];
    }
}

#define SPT 4
__global__ __launch_bounds__(256) void k_final(const float2* __restrict__ q,
                                               const float2* __restrict__ p,
                                               const float2* __restrict__ x,
                                               int K,
                                               const float* __restrict__ thetaAll,
                                               const float* __restrict__ lamAll,
                                               float* __restrict__ out, float c){
    __shared__ float th[21*12];
    __shared__ float lm[21*12];
    for(int j=threadIdx.x;j<252;j+=blockDim.x){ th[j]=thetaAll[j]; lm[j]=lamAll[j]; }
    __syncthreads();

    const int nth = gridDim.x*blockDim.x;
    const int base = blockIdx.x*blockDim.x + threadIdx.x;

    float q0v[SPT],q1v[SPT],p0v[SPT],p1v[SPT],a0v[SPT],a1v[SPT];
    int idxv[SPT];
    #pragma unroll
    for(int t=0;t<SPT;t++){
        int i = base + t*nth;
        idxv[t]=i;
        int ic = (i<K)?i:0;
        float2 qq=q[ic]; float2 pp=p[ic];
        q0v[t]=qq.x; q1v[t]=qq.y; p0v[t]=pp.x; p1v[t]=pp.y;
        a0v[t]=0.f; a1v[t]=0.f;            // dot_p accumulator (sum_k B_k)
    }

    for(int k=0;k<NIT;k++){
        const float* T = th + k*12;
        const float* L = lm + (k+1)*12;
        float t1_00=T[0],t1_01=T[1],t1_10=T[2],t1_11=T[3];
        float t2_00=T[6],t2_01=T[7],t2_10=T[8],t2_11=T[9],b2_0=T[10],b2_1=T[11];
        float L1_00=L[0],L1_01=L[1],L1_10=L[2],L1_11=L[3];
        float L2_00=L[6],L2_01=L[7],L2_10=L[8],L2_11=L[9],lb2_0=L[10],lb2_1=L[11];
        #pragma unroll
        for(int t=0;t<SPT;t++){
            float u0=t2_00*q0v[t]+t2_01*q1v[t]+b2_0;
            float u1=t2_10*q0v[t]+t2_11*q1v[t]+b2_1;
            float h0=fast_tanh(u0), h1=fast_tanh(u1);
            float s0=1.f-h0*h0, s1=1.f-h1*h1;
            float a0=t1_00*p0v[t]+t1_10*p1v[t];
            float a1=t1_01*p0v[t]+t1_11*p1v[t];
            float w0=a0*s0, w1=a1*s1;
            float r0=-2.f*a0*h0*s0, r1=-2.f*a1*h1*s1;
            float lp0=L1_00*p0v[t]+L1_10*p1v[t];    // (Lam1^T p)
            float lp1=L1_01*p0v[t]+L1_11*p1v[t];
            float z0=L2_00*q0v[t]+L2_01*q1v[t]+lb2_0; // (Lam2 q + lamb2)
            float z1=L2_10*q0v[t]+L2_11*q1v[t]+lb2_1;
            float m0=lp0*s0 + r0*z0;
            float m1=lp1*s1 + r1*z1;
            // B = T2^T m + Lam2^T w
            a0v[t] += t2_00*m0 + t2_10*m1 + L2_00*w0 + L2_10*w1;
            a1v[t] += t2_01*m0 + t2_11*m1 + L2_01*w0 + L2_11*w1;
        }
    }

    // epilogue at Theta_20
    {
        const float* T = th + 20*12;
        float t1_00=T[0],t1_01=T[1],t1_10=T[2],t1_11=T[3],b1_0=T[4],b1_1=T[5];
        float t2_00=T[6],t2_01=T[7],t2_10=T[8],t2_11=T[9],b2_0=T[10],b2_1=T[11];
        #pragma unroll
        for(int t=0;t<SPT;t++){
            int i = idxv[t];
            if(i >= K) continue;
            float u0=t2_00*q0v[t]+t2_01*q1v[t]+b2_0;
            float u1=t2_10*q0v[t]+t2_11*q1v[t]+b2_1;
            float h0=fast_tanh(u0), h1=fast_tanh(u1);
            float s0=1.f-h0*h0, s1=1.f-h1*h1;
            float a0=t1_00*p0v[t]+t1_10*p1v[t];
            float a1=t1_01*p0v[t]+t1_11*p1v[t];
            float w0=a0*s0, w1=a1*s1;
            // dot_q = T1 h + b1
            out[2*i+0] = t1_00*h0 + t1_01*h1 + b1_0;
            out[2*i+1] = t1_10*h0 + t1_11*h1 + b1_1;
            // dot_p = c*(LR*sum_k B_k - T2^T w)
            float dir0 = t2_00*w0 + t2_10*w1;
            float dir1 = t2_01*w0 + t2_11*w1;
            out[2*K+2*i+0] = c*(LR*a0v[t] - dir0);
            out[2*K+2*i+1] = c*(LR*a1v[t] - dir1);
            // dot_x = T1 tanh(T2 x + b2) + b1
            float2 xx = x[i];
            float xu0=t2_00*xx.x+t2_01*xx.y+b2_0;
            float xu1=t2_10*xx.x+t2_11*xx.y+b2_1;
            float xh0=fast_tanh(xu0), xh1=fast_tanh(xu1);
            out[4*K+2*i+0] = t1_00*xh0 + t1_01*xh1 + b1_0;
            out[4*K+2*i+1] = t1_10*xh0 + t1_11*xh1 + b1_1;
        }
    }
}

extern "C" void kernel_launch(void* const* d_in, const int* in_sizes, int n_in,
                              void* d_out, int out_size, void* d_ws, size_t ws_size,
                              hipStream_t stream) {
    const float* inp = (const float*)d_in[1];
    const int K = in_sizes[1]/6;
    const float2* q = (const float2*)inp;
    const float2* p = q + K;
    const float2* x = q + 2*K;

    double* stats = (double*)d_ws;                                    // [21][40]
    float* theta  = (float*)((char*)d_ws + 21*STRIDE_STATS*sizeof(double));
    float* lam    = theta + 21*12;
    float* ksym   = lam + 21*12;
    float* ksymb  = ksym + 16;
    const float c = 1.0f/(2.0f*(float)K);

    hipMemsetAsync(stats, 0, 21*STRIDE_STATS*sizeof(double), stream);
    k_setup<<<1,64,0,stream>>>((const float*)d_in[2],(const float*)d_in[3],
                               (const float*)d_in[4],(const float*)d_in[5],
                               (const float*)d_in[6],(const float*)d_in[7],
                               theta, ksym, ksymb);
    for(int k=0;k<=NIT;k++){
        k_reduce<<<256,256,0,stream>>>(q, p, K, theta + k*12, stats + k*STRIDE_STATS);
        if(k<NIT)
            k_update<<<1,64,0,stream>>>(stats + k*STRIDE_STATS, theta + k*12,
                                        theta + (k+1)*12, ksym, ksymb, c);
    }
    k_backward<<<1,64,0,stream>>>(stats, theta, lam, ksym, ksymb, c);
    k_final<<<1024,256,0,stream>>>(q, p, x, K, theta, lam, (float*)d_out, c);
}